// Round 4
// baseline (1162.465 us; speedup 1.0000x reference)
//
#include <hip/hip_runtime.h>
#include <cstdint>

#define H 256
#define MT 64
#define PBLOCKS 512   // persistent blocks: 2 per CU (LDS-limited)

typedef _Float16 half8 __attribute__((ext_vector_type(8)));
typedef float floatx4 __attribute__((ext_vector_type(4)));

__device__ __forceinline__ float fast_tanh(float v) {
    v = fminf(fmaxf(v, -15.f), 15.f);
    float e = __expf(2.f * v);
    return (e - 1.f) / (e + 1.f);
}

// -------- setup: zero out + Z, and W1 [k][n] fp32 -> w1c f16 fragment order -
// w1c chunk t = ((ct*4 + s)*2 + kc), each 512 halves laid out [lane][h]:
//   element = W1[k = s*64 + kc*32 + (lane>>4)*8 + h][n = ct*16 + (lane&15)]
__global__ void setup_kernel(const float* __restrict__ W1,
                             float4* __restrict__ out4, float* __restrict__ Z,
                             _Float16* __restrict__ w1c, int total4, int G) {
    int i = blockIdx.x * 256 + threadIdx.x;
    if (i < total4) out4[i] = make_float4(0.f, 0.f, 0.f, 0.f);
    if (i < G) Z[i] = 0.f;
    if (i < H * H) {
        int r = i & 511;
        int lane = r >> 3, h = r & 7;
        int t = i >> 9;
        int kc = t & 1, s = (t >> 1) & 3, ct = t >> 3;
        int mm = lane & 15, qq = lane >> 4;
        int col = ct * 16 + mm;
        int k = s * 64 + kc * 32 + qq * 8 + h;
        w1c[i] = (_Float16)W1[k * H + col];
    }
}

// -------- persistent fused kernel -------------------------------------------
// 512 blocks x 256 thr (4 waves); each block owns a CONTIGUOUS run of 64-row
// tiles. Per tile: [issue next tile's 16 float4 loads] -> MFMA (As[buf]) ->
// epilogue (tanh dot w2 -> exp weight) -> Phase B (global fp32 re-read,
// L2/L3-hot, unroll 8; accumulator carried ACROSS tiles, atomic flush only at
// graph boundaries) -> cvt+store next tile to As[buf^1]. Double-buffered LDS
// keeps HBM loads in flight through the whole compute chain.
__global__ __launch_bounds__(256, 2) void fused_kernel(
    const float* __restrict__ x, const _Float16* __restrict__ w1c,
    const float* __restrict__ b1, const float* __restrict__ w2,
    const int* __restrict__ batch,
    float* __restrict__ out, float* __restrict__ Z, int N, int nt, int tpb) {
    __shared__ _Float16 As[2][64][256];
    __shared__ float sred[4][64];
    __shared__ float sexp[64];
    __shared__ int gid[64];

    const int tid = threadIdx.x;
    const int wv = tid >> 6;
    const int lane = tid & 63;
    const int m = lane & 15;
    const int q = lane >> 4;

    const int t0 = blockIdx.x * tpb;
    const int t1 = (t0 + tpb < nt) ? (t0 + tpb) : nt;
    if (t0 >= nt) return;

    // staging assignment: thread -> (row, 16-float chunk), swizzled 8-half grp
    const int srow = tid >> 2;
    const int sc4 = tid & 3;
    const int sg0 = (sc4 * 2) ^ (srow & 7);
    const int sg1 = (sc4 * 2 + 1) ^ (srow & 7);

    float b1c[4], w2c[4];
#pragma unroll
    for (int ni = 0; ni < 4; ++ni) {
        int c = wv * 64 + ni * 16 + m;
        b1c[ni] = b1[c];
        w2c[ni] = w2[c];
    }

    float4 f[4][4];   // prefetch registers: full 64x256 tile slice, 16B x16
    bool nok;

#define LOAD16(T)                                                          \
    {                                                                      \
        const float* sb = x + (size_t)((T) * MT + srow) * H + sc4 * 16;    \
        _Pragma("unroll") for (int s = 0; s < 4; ++s) {                    \
            const float4* p = (const float4*)(sb + s * 64);                \
            f[s][0] = p[0]; f[s][1] = p[1]; f[s][2] = p[2]; f[s][3] = p[3];\
        }                                                                  \
    }

#define CVT_STORE(B)                                                       \
    {                                                                      \
        _Pragma("unroll") for (int s = 0; s < 4; ++s) {                    \
            half8 h0, h1;                                                  \
            h0[0] = (_Float16)f[s][0].x; h0[1] = (_Float16)f[s][0].y;      \
            h0[2] = (_Float16)f[s][0].z; h0[3] = (_Float16)f[s][0].w;      \
            h0[4] = (_Float16)f[s][1].x; h0[5] = (_Float16)f[s][1].y;      \
            h0[6] = (_Float16)f[s][1].z; h0[7] = (_Float16)f[s][1].w;      \
            h1[0] = (_Float16)f[s][2].x; h1[1] = (_Float16)f[s][2].y;      \
            h1[2] = (_Float16)f[s][2].z; h1[3] = (_Float16)f[s][2].w;      \
            h1[4] = (_Float16)f[s][3].x; h1[5] = (_Float16)f[s][3].y;      \
            h1[6] = (_Float16)f[s][3].z; h1[7] = (_Float16)f[s][3].w;      \
            *(half8*)&As[B][srow][s * 64 + sg0 * 8] = h0;                  \
            *(half8*)&As[B][srow][s * 64 + sg1 * 8] = h1;                  \
        }                                                                  \
    }

    // prologue: stage tile t0 into As[0]
    {
        bool ok = (t0 * MT + srow) < N;
        if (ok) { LOAD16(t0); CVT_STORE(0); }
    }
    __syncthreads();

    // Phase-B accumulator state, carried across tiles (rows are contiguous)
    float acc2 = 0.f, zacc = 0.f;
    int cur = -1;

    for (int t = t0; t < t1; ++t) {
        const int buf = (t - t0) & 1;
        const int row0 = t * MT;

        // issue next tile's global loads EARLY (cover MFMA + epi + Phase B)
        nok = false;
        if (t + 1 < t1) {
            nok = ((t + 1) * MT + srow) < N;
            if (nok) LOAD16(t + 1);
        }

        floatx4 acc[4][4];
#pragma unroll
        for (int mi = 0; mi < 4; ++mi)
#pragma unroll
            for (int ni = 0; ni < 4; ++ni) {
                floatx4 v;
                v[0] = b1c[ni]; v[1] = b1c[ni]; v[2] = b1c[ni]; v[3] = b1c[ni];
                acc[mi][ni] = v;
            }

        for (int s = 0; s < 4; ++s) {
            half8 bf[4][2];
#pragma unroll
            for (int ni = 0; ni < 4; ++ni) {
                int ct = wv * 4 + ni;
#pragma unroll
                for (int kc = 0; kc < 2; ++kc) {
                    int chunk = ((ct << 2) | s) * 2 + kc;
                    bf[ni][kc] = *(const half8*)(w1c + ((size_t)chunk << 9) + lane * 8);
                }
            }
            half8 af[4][2];
#pragma unroll
            for (int mi = 0; mi < 4; ++mi) {
                int r = mi * 16 + m;
#pragma unroll
                for (int kc = 0; kc < 2; ++kc) {
                    int g = (kc * 4 + q) ^ (r & 7);
                    af[mi][kc] = *(const half8*)&As[buf][r][s * 64 + g * 8];
                }
            }
#pragma unroll
            for (int mi = 0; mi < 4; ++mi)
#pragma unroll
                for (int ni = 0; ni < 4; ++ni) {
                    acc[mi][ni] = __builtin_amdgcn_mfma_f32_16x16x32_f16(
                        af[mi][0], bf[ni][0], acc[mi][ni], 0, 0, 0);
                    acc[mi][ni] = __builtin_amdgcn_mfma_f32_16x16x32_f16(
                        af[mi][1], bf[ni][1], acc[mi][ni], 0, 0, 0);
                }
        }

        // epilogue: s_row = sum_j w2[j] * tanh(h[row][j])  (b1 already in acc)
#pragma unroll
        for (int mi = 0; mi < 4; ++mi) {
#pragma unroll
            for (int r = 0; r < 4; ++r) {
                float v = 0.f;
#pragma unroll
                for (int ni = 0; ni < 4; ++ni)
                    v += w2c[ni] * fast_tanh(acc[mi][ni][r]);
                v += __shfl_xor(v, 1);
                v += __shfl_xor(v, 2);
                v += __shfl_xor(v, 4);
                v += __shfl_xor(v, 8);
                if (m == 0) sred[wv][mi * 16 + q * 4 + r] = v;
            }
        }
        __syncthreads();
        if (tid < MT) {
            int row = row0 + tid;
            if (row < N) {
                float sc = sred[0][tid] + sred[1][tid] + sred[2][tid] + sred[3][tid];
                sexp[tid] = __expf(sc);   // |sc| <= sum|w2| ~ 13: no overflow
                gid[tid] = batch[row];
            } else {
                sexp[tid] = 0.f;          // contributes nothing
                gid[tid] = batch[N - 1];  // valid id; flush of prior data ok
            }
        }
        __syncthreads();

        // Phase B: weighted segment accumulate. Thread tid owns column tid.
        // Rows just streamed -> L2/L3-hot fp32 re-read (exact numerics).
        {
            const int nval = (N - row0 < MT) ? (N - row0) : MT;
            const float* px = x + (size_t)row0 * H + tid;
#pragma unroll 8
            for (int r = 0; r < nval; ++r) {
                int g = gid[r];
                float w = sexp[r];
                float xv = px[(size_t)r * H];
                if (g != cur) {                     // block-uniform branch
                    if (cur >= 0) {
                        atomicAdd(&out[(size_t)cur * H + tid], acc2);
                        if (tid == 0) atomicAdd(&Z[cur], zacc);
                    }
                    acc2 = 0.f; zacc = 0.f; cur = g;
                }
                acc2 = fmaf(w, xv, acc2);
                zacc += w;
            }
        }

        // stage next tile into the other buffer (loads issued at loop top)
        if (t + 1 < t1 && nok) CVT_STORE(buf ^ 1);
        __syncthreads();
    }

    if (cur >= 0) {
        atomicAdd(&out[(size_t)cur * H + tid], acc2);
        if (tid == 0) atomicAdd(&Z[cur], zacc);
    }
#undef LOAD16
#undef CVT_STORE
}

// -------- normalize in place ------------------------------------------------
__global__ void normalize_kernel(float4* __restrict__ out4,
                                 const float* __restrict__ Z, int total4) {
    int i = blockIdx.x * 256 + threadIdx.x;
    if (i < total4) {
        float s = Z[i >> 6];
        if (s > 0.f) {
            float inv = 1.f / s;
            float4 v = out4[i];
            v.x *= inv; v.y *= inv; v.z *= inv; v.w *= inv;
            out4[i] = v;
        } else {
            out4[i] = make_float4(0.f, 0.f, 0.f, 0.f);
        }
    }
}

extern "C" void kernel_launch(void* const* d_in, const int* in_sizes, int n_in,
                              void* d_out, int out_size, void* d_ws, size_t ws_size,
                              hipStream_t stream) {
    const float* x = (const float*)d_in[0];
    const int* batch = (const int*)d_in[1];
    const float* W1 = (const float*)d_in[2];
    const float* b1 = (const float*)d_in[3];
    const float* w2 = (const float*)d_in[4];
    float* out = (float*)d_out;

    const int N = in_sizes[0] / H;
    const int G = out_size / H;

    // workspace: Z[G] | w1c (128 KB)
    char* ws = (char*)d_ws;
    float* Z = (float*)ws;
    size_t off = (size_t)G * sizeof(float);
    off = (off + 15) & ~(size_t)15;
    _Float16* w1c = (_Float16*)(ws + off);

    const int total4 = (G * H) / 4;
    int setup_items = (total4 > H * H) ? total4 : (H * H);
    setup_kernel<<<(setup_items + 255) / 256, 256, 0, stream>>>(
        W1, (float4*)out, Z, w1c, total4, G);

    const int nt = (N + MT - 1) / MT;
    const int tpb = (nt + PBLOCKS - 1) / PBLOCKS;
    fused_kernel<<<PBLOCKS, 256, 0, stream>>>(
        x, w1c, b1, w2, batch, out, Z, N, nt, tpb);

    normalize_kernel<<<(total4 + 255) / 256, 256, 0, stream>>>(
        (float4*)out, Z, total4);
}